// Round 3
// baseline (4480.775 us; speedup 1.0000x reference)
//
#include <hip/hip_runtime.h>

// GCN 2-layer: h1 = leaky(Ahat @ (x@W1^T) + b1); h2 = Ahat @ (h1@W2^T) + b2
// Ahat = D^-1/2 (A + I) D^-1/2 factorized as dinv[dst] * sum(dinv[src]*h[src]) + self term.

#define THREADS 256

__global__ __launch_bounds__(THREADS)
void deg_kernel(const int* __restrict__ dst, float* __restrict__ deg, int E) {
    int e = blockIdx.x * THREADS + threadIdx.x;
    if (e < E) unsafeAtomicAdd(&deg[dst[e]], 1.0f);
}

__global__ __launch_bounds__(THREADS)
void dinv_kernel(float* __restrict__ deg, int n) {
    int i = blockIdx.x * THREADS + threadIdx.x;
    if (i < n) deg[i] = rsqrtf(deg[i] + 1.0f);   // +1 = self loop; always > 0
}

// G[i][j] = dinv[i] * sum_k X[i][k] * W[j][k];  W row-major [DO][128], DK=128 fixed.
template <int DO>
__global__ __launch_bounds__(THREADS)
void gemm_scale(const float* __restrict__ X, const float* __restrict__ W,
                const float* __restrict__ dinv, float* __restrict__ G, int nrows) {
    constexpr int PAD = 132;                 // stride ≡ 4 mod 32 dwords: b128 reads at BW floor
    constexpr int R = THREADS / DO;          // rows per block-iter (2 or 4)
    __shared__ float Ws[DO * PAD];
    __shared__ float Xs[R * 128];

    // stage W into LDS (DO*128 floats, float4)
    for (int idx = threadIdx.x; idx < DO * 32; idx += THREADS) {
        int row = idx >> 5, c4 = idx & 31;
        float4 w = ((const float4*)W)[idx];
        *(float4*)&Ws[row * PAD + c4 * 4] = w;
    }
    __syncthreads();

    const int j = threadIdx.x % DO;
    const int r = threadIdx.x / DO;

    for (int base = blockIdx.x * R; base < nrows; base += gridDim.x * R) {
        for (int idx = threadIdx.x; idx < R * 32; idx += THREADS) {
            int rr = idx >> 5, c4 = idx & 31;
            int row = base + rr;
            float4 xv = (row < nrows) ? ((const float4*)(X + (size_t)row * 128))[c4]
                                      : make_float4(0.f, 0.f, 0.f, 0.f);
            *(float4*)&Xs[rr * 128 + c4 * 4] = xv;
        }
        __syncthreads();
        int row = base + r;
        if (row < nrows) {
            float acc = 0.f;
#pragma unroll
            for (int k = 0; k < 128; k += 4) {
                float4 w = *(const float4*)&Ws[j * PAD + k];
                float4 xv = *(const float4*)&Xs[r * 128 + k];
                acc = fmaf(w.x, xv.x, acc);
                acc = fmaf(w.y, xv.y, acc);
                acc = fmaf(w.z, xv.z, acc);
                acc = fmaf(w.w, xv.w, acc);
            }
            G[(size_t)row * DO + j] = dinv[row] * acc;
        }
        __syncthreads();
    }
}

// acc[dst] += g[src] for every edge; DO/4 threads per edge, float4 gather + 4 atomics.
template <int DO>
__global__ __launch_bounds__(THREADS)
void scatter_kernel(const int* __restrict__ src, const int* __restrict__ dst,
                    const float* __restrict__ g, float* __restrict__ acc, int E) {
    constexpr int LPE = DO / 4;              // lanes per edge: 32 or 16
    long long tid = (long long)blockIdx.x * THREADS + threadIdx.x;
    int e = (int)(tid / LPE);
    int f = ((int)(tid % LPE)) * 4;
    if (e >= E) return;
    int s = src[e], d = dst[e];
    float4 v = *(const float4*)(g + (size_t)s * DO + f);
    float* p = acc + (size_t)d * DO + f;
    unsafeAtomicAdd(p + 0, v.x);
    unsafeAtomicAdd(p + 1, v.y);
    unsafeAtomicAdd(p + 2, v.z);
    unsafeAtomicAdd(p + 3, v.w);
}

// out[i][:] = act(dinv[i]*(acc[i][:] + g[i][:]) + bias)   (acc == out, in-place)
template <int DO, bool LEAKY>
__global__ __launch_bounds__(THREADS)
void finish_kernel(float* __restrict__ out, const float* __restrict__ g,
                   const float* __restrict__ dinv, const float* __restrict__ bias, int n) {
    constexpr int C4 = DO / 4;
    int idx = blockIdx.x * THREADS + threadIdx.x;
    int total = n * C4;
    if (idx >= total) return;
    int i = idx / C4;
    int c4 = idx % C4;
    float di = dinv[i];
    float4 a = ((const float4*)out)[idx];
    float4 gv = ((const float4*)g)[idx];
    float4 bv = ((const float4*)bias)[c4];
    float4 r;
    r.x = di * (a.x + gv.x) + bv.x;
    r.y = di * (a.y + gv.y) + bv.y;
    r.z = di * (a.z + gv.z) + bv.z;
    r.w = di * (a.w + gv.w) + bv.w;
    if (LEAKY) {
        r.x = r.x > 0.f ? r.x : 0.01f * r.x;
        r.y = r.y > 0.f ? r.y : 0.01f * r.y;
        r.z = r.z > 0.f ? r.z : 0.01f * r.z;
        r.w = r.w > 0.f ? r.w : 0.01f * r.w;
    }
    ((float4*)out)[idx] = r;
}

extern "C" void kernel_launch(void* const* d_in, const int* in_sizes, int n_in,
                              void* d_out, int out_size, void* d_ws, size_t ws_size,
                              hipStream_t stream) {
    const float* x  = (const float*)d_in[0];
    const int*   ei = (const int*)d_in[1];
    const float* W1 = (const float*)d_in[2];
    const float* b1 = (const float*)d_in[3];
    const float* W2 = (const float*)d_in[4];
    const float* b2 = (const float*)d_in[5];

    const int N = in_sizes[0] / 128;
    const int E = in_sizes[1] / 2;
    const int* src = ei;
    const int* dst = ei + E;

    char* ws = (char*)d_ws;
    size_t off = 0;
    float* dinv = (float*)(ws + off);
    off += ((size_t)N * 4 + 511) & ~(size_t)511;
    float* g1 = (float*)(ws + off);
    float* g2 = g1;                           // g1 dead after finish1; reuse region

    float* h1 = (float*)d_out;                // N*128, also scatter-accumulator 1
    float* h2 = h1 + (size_t)N * 128;         // N*64,  also scatter-accumulator 2

    // zero degree buffer + both output accumulators
    hipMemsetAsync(dinv, 0, (size_t)N * 4, stream);
    hipMemsetAsync(d_out, 0, (size_t)out_size * 4, stream);

    deg_kernel<<<(E + THREADS - 1) / THREADS, THREADS, 0, stream>>>(dst, dinv, E);
    dinv_kernel<<<(N + THREADS - 1) / THREADS, THREADS, 0, stream>>>(dinv, N);

    // ---- layer 1 ----
    gemm_scale<128><<<2048, THREADS, 0, stream>>>(x, W1, dinv, g1, N);
    {
        long long tot = (long long)E * 32;
        int blocks = (int)((tot + THREADS - 1) / THREADS);
        scatter_kernel<128><<<blocks, THREADS, 0, stream>>>(src, dst, g1, h1, E);
    }
    finish_kernel<128, true><<<(N * 32 + THREADS - 1) / THREADS, THREADS, 0, stream>>>(
        h1, g1, dinv, b1, N);

    // ---- layer 2 ----
    gemm_scale<64><<<2048, THREADS, 0, stream>>>(h1, W2, dinv, g2, N);
    {
        long long tot = (long long)E * 16;
        int blocks = (int)((tot + THREADS - 1) / THREADS);
        scatter_kernel<64><<<blocks, THREADS, 0, stream>>>(src, dst, g2, h2, E);
    }
    finish_kernel<64, false><<<(N * 16 + THREADS - 1) / THREADS, THREADS, 0, stream>>>(
        h2, g2, dinv, b2, N);
}

// Round 4
// 739.724 us; speedup vs baseline: 6.0574x; 6.0574x over previous
//
#include <hip/hip_runtime.h>

// GCN 2-layer, atomic-free aggregation via per-call CSR (counting sort by dst).
// h = leaky(Ahat @ (x@W1^T) + b1); out = Ahat @ (h@W2^T) + b2
// Ahat = D^-1/2 (A+I) D^-1/2 factorized: out[i] = dinv[i]*(sum_{e:dst=i} g[src] + g[i]) + b,
// with g = dinv * (X @ W^T) so no per-edge norm is needed.

#define THREADS 256

__global__ __launch_bounds__(THREADS)
void count_kernel(const int* __restrict__ dst, int* __restrict__ counts, int E) {
    int e = blockIdx.x * THREADS + threadIdx.x;
    if (e < E) atomicAdd(&counts[dst[e]], 1);
}

// per-block exclusive scan of counts -> rowptr (block-local); block totals -> bsum
__global__ __launch_bounds__(THREADS)
void scanA(const int* __restrict__ counts, int* __restrict__ rowptr,
           int* __restrict__ bsum, int n) {
    __shared__ int s[THREADS];
    int i = blockIdx.x * THREADS + threadIdx.x;
    int v = (i < n) ? counts[i] : 0;
    s[threadIdx.x] = v;
    __syncthreads();
    for (int off = 1; off < THREADS; off <<= 1) {
        int a = (threadIdx.x >= off) ? s[threadIdx.x - off] : 0;
        __syncthreads();
        s[threadIdx.x] += a;
        __syncthreads();
    }
    if (i < n) rowptr[i] = s[threadIdx.x] - v;          // exclusive
    if (threadIdx.x == THREADS - 1) bsum[blockIdx.x] = s[threadIdx.x];
}

// single-block exclusive scan of block sums (nb <= 512)
__global__ __launch_bounds__(512)
void scanB(const int* __restrict__ bsum, int* __restrict__ boff, int nb) {
    __shared__ int s[512];
    int t = threadIdx.x;
    int v = (t < nb) ? bsum[t] : 0;
    s[t] = v;
    __syncthreads();
    for (int off = 1; off < 512; off <<= 1) {
        int a = (t >= off) ? s[t - off] : 0;
        __syncthreads();
        s[t] += a;
        __syncthreads();
    }
    if (t < nb) boff[t] = s[t] - v;
}

// finalize: global rowptr, cursor copy for fill, dinv = rsqrt(deg_in + 1)
__global__ __launch_bounds__(THREADS)
void scanC(int* __restrict__ rowptr, int* __restrict__ cursor, float* __restrict__ dinv,
           const int* __restrict__ counts, const int* __restrict__ boff, int n) {
    int i = blockIdx.x * THREADS + threadIdx.x;
    if (i >= n) return;
    int r = rowptr[i] + boff[blockIdx.x];
    rowptr[i] = r;
    cursor[i] = r;
    dinv[i] = rsqrtf((float)counts[i] + 1.0f);
}

__global__ __launch_bounds__(THREADS)
void fill_kernel(const int* __restrict__ src, const int* __restrict__ dst,
                 int* __restrict__ cursor, int* __restrict__ csr, int E) {
    int e = blockIdx.x * THREADS + threadIdx.x;
    if (e < E) {
        int pos = atomicAdd(&cursor[dst[e]], 1);
        csr[pos] = src[e];
    }
}

// G[i][j] = dinv[i] * sum_k X[i][k] * W[j][k];  W row-major [DO][128], K=128 fixed.
template <int DO>
__global__ __launch_bounds__(THREADS)
void gemm_scale(const float* __restrict__ X, const float* __restrict__ W,
                const float* __restrict__ dinv, float* __restrict__ G, int nrows) {
    constexpr int PAD = 132;
    constexpr int R = THREADS / DO;
    __shared__ float Ws[DO * PAD];
    __shared__ float Xs[R * 128];

    for (int idx = threadIdx.x; idx < DO * 32; idx += THREADS) {
        int row = idx >> 5, c4 = idx & 31;
        float4 w = ((const float4*)W)[idx];
        *(float4*)&Ws[row * PAD + c4 * 4] = w;
    }
    __syncthreads();

    const int j = threadIdx.x % DO;
    const int r = threadIdx.x / DO;

    for (int base = blockIdx.x * R; base < nrows; base += gridDim.x * R) {
        for (int idx = threadIdx.x; idx < R * 32; idx += THREADS) {
            int rr = idx >> 5, c4 = idx & 31;
            int row = base + rr;
            float4 xv = (row < nrows) ? ((const float4*)(X + (size_t)row * 128))[c4]
                                      : make_float4(0.f, 0.f, 0.f, 0.f);
            *(float4*)&Xs[rr * 128 + c4 * 4] = xv;
        }
        __syncthreads();
        int row = base + r;
        if (row < nrows) {
            float acc = 0.f;
#pragma unroll
            for (int k = 0; k < 128; k += 4) {
                float4 w = *(const float4*)&Ws[j * PAD + k];
                float4 xv = *(const float4*)&Xs[r * 128 + k];
                acc = fmaf(w.x, xv.x, acc);
                acc = fmaf(w.y, xv.y, acc);
                acc = fmaf(w.z, xv.z, acc);
                acc = fmaf(w.w, xv.w, acc);
            }
            G[(size_t)row * DO + j] = dinv[row] * acc;
        }
        __syncthreads();
    }
}

// One wave per node: gather all in-edge rows of g, fuse self term + dinv scale + bias + act.
template <int DO, bool LEAKY>
__global__ __launch_bounds__(THREADS)
void aggregate(const int* __restrict__ rowptr, const int* __restrict__ counts,
               const int* __restrict__ csr, const float* __restrict__ g,
               const float* __restrict__ dinv, const float* __restrict__ bias,
               float* __restrict__ out, int n) {
    int lane = threadIdx.x & 63;
    int node = blockIdx.x * (THREADS / 64) + (threadIdx.x >> 6);
    if (node >= n) return;
    int beg = rowptr[node], cnt = counts[node];

    if (DO == 128) {
        float ax = 0.f, ay = 0.f;
        for (int base = 0; base < cnt; base += 64) {
            int m = cnt - base; if (m > 64) m = 64;
            int sv = (base + lane < cnt) ? csr[beg + base + lane] : 0;
            for (int i = 0; i < m; i++) {
                int s = __shfl(sv, i);
                float2 v = *(const float2*)(g + (size_t)s * 128 + lane * 2);
                ax += v.x; ay += v.y;
            }
        }
        float2 self = *(const float2*)(g + (size_t)node * 128 + lane * 2);
        float2 bv = *(const float2*)(bias + lane * 2);
        float di = dinv[node];
        float rx = di * (ax + self.x) + bv.x;
        float ry = di * (ay + self.y) + bv.y;
        if (LEAKY) {
            rx = rx > 0.f ? rx : 0.01f * rx;
            ry = ry > 0.f ? ry : 0.01f * ry;
        }
        *(float2*)(out + (size_t)node * 128 + lane * 2) = make_float2(rx, ry);
    } else {
        float ax = 0.f;
        for (int base = 0; base < cnt; base += 64) {
            int m = cnt - base; if (m > 64) m = 64;
            int sv = (base + lane < cnt) ? csr[beg + base + lane] : 0;
            for (int i = 0; i < m; i++) {
                int s = __shfl(sv, i);
                ax += g[(size_t)s * 64 + lane];
            }
        }
        float r = dinv[node] * (ax + g[(size_t)node * 64 + lane]) + bias[lane];
        if (LEAKY) r = r > 0.f ? r : 0.01f * r;
        out[(size_t)node * 64 + lane] = r;
    }
}

extern "C" void kernel_launch(void* const* d_in, const int* in_sizes, int n_in,
                              void* d_out, int out_size, void* d_ws, size_t ws_size,
                              hipStream_t stream) {
    const float* x  = (const float*)d_in[0];
    const int*   ei = (const int*)d_in[1];
    const float* W1 = (const float*)d_in[2];
    const float* b1 = (const float*)d_in[3];
    const float* W2 = (const float*)d_in[4];
    const float* b2 = (const float*)d_in[5];

    const int N = in_sizes[0] / 128;
    const int E = in_sizes[1] / 2;
    const int* src = ei;
    const int* dst = ei + E;

    const int NB = (N + THREADS - 1) / THREADS;      // scan blocks (<= 512 required)

    char* ws = (char*)d_ws;
    size_t off = 0;
    auto alloc = [&](size_t bytes) { char* p = ws + off; off = (off + bytes + 511) & ~(size_t)511; return p; };
    int*   counts = (int*)alloc((size_t)N * 4);
    int*   rowptr = (int*)alloc((size_t)N * 4);
    int*   cursor = (int*)alloc((size_t)N * 4);
    int*   bsum   = (int*)alloc((size_t)NB * 4);
    int*   boff   = (int*)alloc((size_t)NB * 4);
    float* dinv   = (float*)alloc((size_t)N * 4);
    int*   csr    = (int*)alloc((size_t)E * 4);
    float* g1     = (float*)alloc((size_t)N * 128 * 4);
    float* g2     = g1;                               // g1 dead before gemm2 writes g2

    float* h1 = (float*)d_out;                        // N*128
    float* h2 = h1 + (size_t)N * 128;                 // N*64

    hipMemsetAsync(counts, 0, (size_t)N * 4, stream);

    const int EB = (E + THREADS - 1) / THREADS;
    count_kernel<<<EB, THREADS, 0, stream>>>(dst, counts, E);
    scanA<<<NB, THREADS, 0, stream>>>(counts, rowptr, bsum, N);
    scanB<<<1, 512, 0, stream>>>(bsum, boff, NB);
    scanC<<<NB, THREADS, 0, stream>>>(rowptr, cursor, dinv, counts, boff, N);
    fill_kernel<<<EB, THREADS, 0, stream>>>(src, dst, cursor, csr, E);

    const int AGB = (N + (THREADS / 64) - 1) / (THREADS / 64);

    // ---- layer 1 ----
    gemm_scale<128><<<2048, THREADS, 0, stream>>>(x, W1, dinv, g1, N);
    aggregate<128, true><<<AGB, THREADS, 0, stream>>>(rowptr, counts, csr, g1, dinv, b1, h1, N);

    // ---- layer 2 ----
    gemm_scale<64><<<2048, THREADS, 0, stream>>>(h1, W2, dinv, g2, N);
    aggregate<64, false><<<AGB, THREADS, 0, stream>>>(rowptr, counts, csr, g2, dinv, b2, h2, N);
}

// Round 5
// 629.364 us; speedup vs baseline: 7.1195x; 1.1754x over previous
//
#include <hip/hip_runtime.h>

// GCN 2-layer, atomic-free aggregation via per-call CSR (counting sort by dst).
// h = leaky(Ahat @ (x@W1^T) + b1); out = Ahat @ (h@W2^T) + b2
// Ahat = D^-1/2 (A+I) D^-1/2 factorized: out[i] = dinv[i]*(sum_{e:dst=i} g[src] + g[i]) + b,
// with g = dinv * (X @ W^T) so no per-edge norm is needed.
// GEMMs run on MFMA with hi/lo bf16 split (3-term) => f32-grade accuracy at bf16 speed.

#define THREADS 256

typedef __attribute__((ext_vector_type(8))) short bf16x8;
typedef __attribute__((ext_vector_type(4))) float f32x4;

__device__ __forceinline__ short f2bf_rne(float f) {
    unsigned u = __builtin_bit_cast(unsigned, f);
    u = u + 0x7fffu + ((u >> 16) & 1u);
    return (short)(u >> 16);
}
__device__ __forceinline__ float bf2f(short h) {
    unsigned u = ((unsigned)(unsigned short)h) << 16;
    return __builtin_bit_cast(float, u);
}

__global__ __launch_bounds__(THREADS)
void count_kernel(const int* __restrict__ dst, int* __restrict__ counts, int E) {
    int e = blockIdx.x * THREADS + threadIdx.x;
    if (e < E) atomicAdd(&counts[dst[e]], 1);
}

// per-block exclusive scan of counts -> rowptr (block-local); block totals -> bsum
__global__ __launch_bounds__(THREADS)
void scanA(const int* __restrict__ counts, int* __restrict__ rowptr,
           int* __restrict__ bsum, int n) {
    __shared__ int s[THREADS];
    int i = blockIdx.x * THREADS + threadIdx.x;
    int v = (i < n) ? counts[i] : 0;
    s[threadIdx.x] = v;
    __syncthreads();
    for (int off = 1; off < THREADS; off <<= 1) {
        int a = (threadIdx.x >= off) ? s[threadIdx.x - off] : 0;
        __syncthreads();
        s[threadIdx.x] += a;
        __syncthreads();
    }
    if (i < n) rowptr[i] = s[threadIdx.x] - v;          // exclusive
    if (threadIdx.x == THREADS - 1) bsum[blockIdx.x] = s[threadIdx.x];
}

// single-block exclusive scan of block sums (nb <= 512)
__global__ __launch_bounds__(512)
void scanB(const int* __restrict__ bsum, int* __restrict__ boff, int nb) {
    __shared__ int s[512];
    int t = threadIdx.x;
    int v = (t < nb) ? bsum[t] : 0;
    s[t] = v;
    __syncthreads();
    for (int off = 1; off < 512; off <<= 1) {
        int a = (t >= off) ? s[t - off] : 0;
        __syncthreads();
        s[t] += a;
        __syncthreads();
    }
    if (t < nb) boff[t] = s[t] - v;
}

// finalize: global rowptr, cursor copy for fill, dinv = rsqrt(deg_in + 1)
__global__ __launch_bounds__(THREADS)
void scanC(int* __restrict__ rowptr, int* __restrict__ cursor, float* __restrict__ dinv,
           const int* __restrict__ counts, const int* __restrict__ boff, int n) {
    int i = blockIdx.x * THREADS + threadIdx.x;
    if (i >= n) return;
    int r = rowptr[i] + boff[blockIdx.x];
    rowptr[i] = r;
    cursor[i] = r;
    dinv[i] = rsqrtf((float)counts[i] + 1.0f);
}

__global__ __launch_bounds__(THREADS)
void fill_kernel(const int* __restrict__ src, const int* __restrict__ dst,
                 int* __restrict__ cursor, int* __restrict__ csr, int E) {
    int e = blockIdx.x * THREADS + threadIdx.x;
    if (e < E) {
        int pos = atomicAdd(&cursor[dst[e]], 1);
        csr[pos] = src[e];
    }
}

// G[i][j] = dinv[i] * sum_k X[i][k] * W[j][k];  W row-major [DO][128], K=128 fixed.
// MFMA 16x16x32 bf16, hi/lo split: x@W ~= xh@wh + xh@wl + xl@wh  (xl@wl ~ 2^-16, dropped).
// Block = 4 waves; wave owns WCT=DO/64 col-tiles; W frags in registers (loop-invariant).
template <int DO>
__global__ __launch_bounds__(THREADS)
void gemm_mfma(const float* __restrict__ X, const float* __restrict__ W,
               const float* __restrict__ dinv, float* __restrict__ G, int nrows) {
    constexpr int WCT = DO / 64;
    const int wid = threadIdx.x >> 6;
    const int lane = threadIdx.x & 63;
    const int l15 = lane & 15;
    const int lhi = lane >> 4;

    // ---- W fragments (hi/lo), registers, loop-invariant ----
    bf16x8 wh[WCT][4], wl[WCT][4];
#pragma unroll
    for (int ct = 0; ct < WCT; ct++) {
        const int j = (wid * WCT + ct) * 16 + l15;           // B col
#pragma unroll
        for (int kc = 0; kc < 4; kc++) {
            const float* wp = W + (size_t)j * 128 + kc * 32 + lhi * 8;
            float4 w0 = *(const float4*)wp;
            float4 w1 = *(const float4*)(wp + 4);
            float wv[8] = {w0.x, w0.y, w0.z, w0.w, w1.x, w1.y, w1.z, w1.w};
#pragma unroll
            for (int t = 0; t < 8; t++) {
                short h = f2bf_rne(wv[t]);
                wh[ct][kc][t] = h;
                wl[ct][kc][t] = f2bf_rne(wv[t] - bf2f(h));
            }
        }
    }

    for (int base = blockIdx.x * 16; base < nrows; base += gridDim.x * 16) {
        const int arow = base + l15;                         // A row this lane loads
        const bool av = arow < nrows;
        const float* xp = X + (size_t)arow * 128;
        bf16x8 ah[4], al[4];
#pragma unroll
        for (int kc = 0; kc < 4; kc++) {
            float4 a0 = make_float4(0.f, 0.f, 0.f, 0.f), a1 = a0;
            if (av) {
                a0 = *(const float4*)(xp + kc * 32 + lhi * 8);
                a1 = *(const float4*)(xp + kc * 32 + lhi * 8 + 4);
            }
            float xv[8] = {a0.x, a0.y, a0.z, a0.w, a1.x, a1.y, a1.z, a1.w};
#pragma unroll
            for (int t = 0; t < 8; t++) {
                short h = f2bf_rne(xv[t]);
                ah[kc][t] = h;
                al[kc][t] = f2bf_rne(xv[t] - bf2f(h));
            }
        }

        f32x4 acc[WCT];
#pragma unroll
        for (int ct = 0; ct < WCT; ct++) acc[ct] = (f32x4){0.f, 0.f, 0.f, 0.f};
#pragma unroll
        for (int kc = 0; kc < 4; kc++) {
#pragma unroll
            for (int ct = 0; ct < WCT; ct++) {
                acc[ct] = __builtin_amdgcn_mfma_f32_16x16x32_bf16(ah[kc], wh[ct][kc], acc[ct], 0, 0, 0);
                acc[ct] = __builtin_amdgcn_mfma_f32_16x16x32_bf16(ah[kc], wl[ct][kc], acc[ct], 0, 0, 0);
                acc[ct] = __builtin_amdgcn_mfma_f32_16x16x32_bf16(al[kc], wh[ct][kc], acc[ct], 0, 0, 0);
            }
        }

        // epilogue: C row = base + lhi*4 + r, col = (wid*WCT+ct)*16 + l15; scale by dinv[row]
        float dv[4];
#pragma unroll
        for (int r = 0; r < 4; r++) {
            int row = base + lhi * 4 + r;
            dv[r] = (row < nrows) ? dinv[row] : 0.f;
        }
#pragma unroll
        for (int ct = 0; ct < WCT; ct++) {
            const int j = (wid * WCT + ct) * 16 + l15;
#pragma unroll
            for (int r = 0; r < 4; r++) {
                int row = base + lhi * 4 + r;
                if (row < nrows) G[(size_t)row * DO + j] = dv[r] * acc[ct][r];
            }
        }
    }
}

// One wave per node: gather all in-edge rows of g, fuse self term + dinv scale + bias + act.
template <int DO, bool LEAKY>
__global__ __launch_bounds__(THREADS)
void aggregate(const int* __restrict__ rowptr, const int* __restrict__ counts,
               const int* __restrict__ csr, const float* __restrict__ g,
               const float* __restrict__ dinv, const float* __restrict__ bias,
               float* __restrict__ out, int n) {
    int lane = threadIdx.x & 63;
    int node = blockIdx.x * (THREADS / 64) + (threadIdx.x >> 6);
    if (node >= n) return;
    int beg = rowptr[node], cnt = counts[node];

    if (DO == 128) {
        float ax = 0.f, ay = 0.f;
        for (int base = 0; base < cnt; base += 64) {
            int m = cnt - base; if (m > 64) m = 64;
            int sv = (base + lane < cnt) ? csr[beg + base + lane] : 0;
            for (int i = 0; i < m; i++) {
                int s = __shfl(sv, i);
                float2 v = *(const float2*)(g + (size_t)s * 128 + lane * 2);
                ax += v.x; ay += v.y;
            }
        }
        float2 self = *(const float2*)(g + (size_t)node * 128 + lane * 2);
        float2 bv = *(const float2*)(bias + lane * 2);
        float di = dinv[node];
        float rx = di * (ax + self.x) + bv.x;
        float ry = di * (ay + self.y) + bv.y;
        if (LEAKY) {
            rx = rx > 0.f ? rx : 0.01f * rx;
            ry = ry > 0.f ? ry : 0.01f * ry;
        }
        *(float2*)(out + (size_t)node * 128 + lane * 2) = make_float2(rx, ry);
    } else {
        float ax = 0.f;
        for (int base = 0; base < cnt; base += 64) {
            int m = cnt - base; if (m > 64) m = 64;
            int sv = (base + lane < cnt) ? csr[beg + base + lane] : 0;
            for (int i = 0; i < m; i++) {
                int s = __shfl(sv, i);
                ax += g[(size_t)s * 64 + lane];
            }
        }
        float r = dinv[node] * (ax + g[(size_t)node * 64 + lane]) + bias[lane];
        if (LEAKY) r = r > 0.f ? r : 0.01f * r;
        out[(size_t)node * 64 + lane] = r;
    }
}

extern "C" void kernel_launch(void* const* d_in, const int* in_sizes, int n_in,
                              void* d_out, int out_size, void* d_ws, size_t ws_size,
                              hipStream_t stream) {
    const float* x  = (const float*)d_in[0];
    const int*   ei = (const int*)d_in[1];
    const float* W1 = (const float*)d_in[2];
    const float* b1 = (const float*)d_in[3];
    const float* W2 = (const float*)d_in[4];
    const float* b2 = (const float*)d_in[5];

    const int N = in_sizes[0] / 128;
    const int E = in_sizes[1] / 2;
    const int* src = ei;
    const int* dst = ei + E;

    const int NB = (N + THREADS - 1) / THREADS;      // scan blocks (<= 512 required)

    char* ws = (char*)d_ws;
    size_t off = 0;
    auto alloc = [&](size_t bytes) { char* p = ws + off; off = (off + bytes + 511) & ~(size_t)511; return p; };
    int*   counts = (int*)alloc((size_t)N * 4);
    int*   rowptr = (int*)alloc((size_t)N * 4);
    int*   cursor = (int*)alloc((size_t)N * 4);
    int*   bsum   = (int*)alloc((size_t)NB * 4);
    int*   boff   = (int*)alloc((size_t)NB * 4);
    float* dinv   = (float*)alloc((size_t)N * 4);
    int*   csr    = (int*)alloc((size_t)E * 4);
    float* g1     = (float*)alloc((size_t)N * 128 * 4);
    float* g2     = g1;                               // g1 dead before gemm2 writes g2

    float* h1 = (float*)d_out;                        // N*128
    float* h2 = h1 + (size_t)N * 128;                 // N*64

    hipMemsetAsync(counts, 0, (size_t)N * 4, stream);

    const int EB = (E + THREADS - 1) / THREADS;
    count_kernel<<<EB, THREADS, 0, stream>>>(dst, counts, E);
    scanA<<<NB, THREADS, 0, stream>>>(counts, rowptr, bsum, N);
    scanB<<<1, 512, 0, stream>>>(bsum, boff, NB);
    scanC<<<NB, THREADS, 0, stream>>>(rowptr, cursor, dinv, counts, boff, N);
    fill_kernel<<<EB, THREADS, 0, stream>>>(src, dst, cursor, csr, E);

    const int AGB = (N + (THREADS / 64) - 1) / (THREADS / 64);

    // ---- layer 1 ----
    gemm_mfma<128><<<2048, THREADS, 0, stream>>>(x, W1, dinv, g1, N);
    aggregate<128, true><<<AGB, THREADS, 0, stream>>>(rowptr, counts, csr, g1, dinv, b1, h1, N);

    // ---- layer 2 ----
    gemm_mfma<64><<<2048, THREADS, 0, stream>>>(h1, W2, dinv, g2, N);
    aggregate<64, false><<<AGB, THREADS, 0, stream>>>(rowptr, counts, csr, g2, dinv, b2, h2, N);
}

// Round 7
// 595.968 us; speedup vs baseline: 7.5185x; 1.0560x over previous
//
#include <hip/hip_runtime.h>

// GCN 2-layer, atomic-free aggregation via per-call CSR (counting sort by dst).
// h = leaky(Ahat @ (x@W1^T) + b1); out = Ahat @ (h@W2^T) + b2
// Ahat = D^-1/2 (A+I) D^-1/2 factorized: out[i] = dinv[i]*(sum_{e:dst=i} g[src] + g[i]) + b,
// with g = dinv * (X @ W^T) so no per-edge norm is needed.
// GEMMs run on MFMA with hi/lo bf16 split (3-term) => f32-grade accuracy at bf16 speed.
// Aggregate/fill are latency-bound -> explicit MLP (multi-edge in flight per wave/thread).

#define THREADS 256

typedef __attribute__((ext_vector_type(8))) short bf16x8;
typedef __attribute__((ext_vector_type(4))) float f32x4;

__device__ __forceinline__ short f2bf_rne(float f) {
    unsigned u = __builtin_bit_cast(unsigned, f);
    u = u + 0x7fffu + ((u >> 16) & 1u);
    return (short)(u >> 16);
}
__device__ __forceinline__ float bf2f(short h) {
    unsigned u = ((unsigned)(unsigned short)h) << 16;
    return __builtin_bit_cast(float, u);
}

// ---- CSR build: 4 edges/thread for atomic MLP ----
__global__ __launch_bounds__(THREADS)
void count_kernel(const int* __restrict__ dst, int* __restrict__ counts, int E, int T) {
    int t = blockIdx.x * THREADS + threadIdx.x;
    int e0 = t, e1 = t + T, e2 = t + 2 * T, e3 = t + 3 * T;
    int d0 = dst[e0], d1 = dst[e1], d2 = dst[e2];
    bool v3 = e3 < E;
    int d3 = v3 ? dst[e3] : 0;
    atomicAdd(&counts[d0], 1);
    atomicAdd(&counts[d1], 1);
    atomicAdd(&counts[d2], 1);
    if (v3) atomicAdd(&counts[d3], 1);
}

__global__ __launch_bounds__(THREADS)
void scanA(const int* __restrict__ counts, int* __restrict__ rowptr,
           int* __restrict__ bsum, int n) {
    __shared__ int s[THREADS];
    int i = blockIdx.x * THREADS + threadIdx.x;
    int v = (i < n) ? counts[i] : 0;
    s[threadIdx.x] = v;
    __syncthreads();
    for (int off = 1; off < THREADS; off <<= 1) {
        int a = (threadIdx.x >= off) ? s[threadIdx.x - off] : 0;
        __syncthreads();
        s[threadIdx.x] += a;
        __syncthreads();
    }
    if (i < n) rowptr[i] = s[threadIdx.x] - v;          // exclusive
    if (threadIdx.x == THREADS - 1) bsum[blockIdx.x] = s[threadIdx.x];
}

__global__ __launch_bounds__(512)
void scanB(const int* __restrict__ bsum, int* __restrict__ boff, int nb) {
    __shared__ int s[512];
    int t = threadIdx.x;
    int v = (t < nb) ? bsum[t] : 0;
    s[t] = v;
    __syncthreads();
    for (int off = 1; off < 512; off <<= 1) {
        int a = (t >= off) ? s[t - off] : 0;
        __syncthreads();
        s[t] += a;
        __syncthreads();
    }
    if (t < nb) boff[t] = s[t] - v;
}

__global__ __launch_bounds__(THREADS)
void scanC(int* __restrict__ rowptr, int* __restrict__ cursor, float* __restrict__ dinv,
           const int* __restrict__ counts, const int* __restrict__ boff, int n) {
    int i = blockIdx.x * THREADS + threadIdx.x;
    if (i >= n) return;
    int r = rowptr[i] + boff[blockIdx.x];
    rowptr[i] = r;
    cursor[i] = r;
    dinv[i] = rsqrtf((float)counts[i] + 1.0f);
}

__global__ __launch_bounds__(THREADS)
void fill_kernel(const int* __restrict__ src, const int* __restrict__ dst,
                 int* __restrict__ cursor, int* __restrict__ csr, int E, int T) {
    int t = blockIdx.x * THREADS + threadIdx.x;
    int e0 = t, e1 = t + T, e2 = t + 2 * T, e3 = t + 3 * T;
    int d0 = dst[e0], d1 = dst[e1], d2 = dst[e2];
    int s0 = src[e0], s1 = src[e1], s2 = src[e2];
    bool v3 = e3 < E;
    int d3 = v3 ? dst[e3] : 0;
    int s3 = v3 ? src[e3] : 0;
    int p0 = atomicAdd(&cursor[d0], 1);
    int p1 = atomicAdd(&cursor[d1], 1);
    int p2 = atomicAdd(&cursor[d2], 1);
    int p3 = v3 ? atomicAdd(&cursor[d3], 1) : 0;
    csr[p0] = s0;
    csr[p1] = s1;
    csr[p2] = s2;
    if (v3) csr[p3] = s3;
}

// G[i][j] = dinv[i] * sum_k X[i][k] * W[j][k];  W row-major [DO][128], K=128 fixed.
// MFMA 16x16x32 bf16, hi/lo split: x@W ~= xh@wh + xh@wl + xl@wh.
template <int DO>
__global__ __launch_bounds__(THREADS)
void gemm_mfma(const float* __restrict__ X, const float* __restrict__ W,
               const float* __restrict__ dinv, float* __restrict__ G, int nrows) {
    constexpr int WCT = DO / 64;
    const int wid = threadIdx.x >> 6;
    const int lane = threadIdx.x & 63;
    const int l15 = lane & 15;
    const int lhi = lane >> 4;

    bf16x8 wh[WCT][4], wl[WCT][4];
#pragma unroll
    for (int ct = 0; ct < WCT; ct++) {
        const int j = (wid * WCT + ct) * 16 + l15;
#pragma unroll
        for (int kc = 0; kc < 4; kc++) {
            const float* wp = W + (size_t)j * 128 + kc * 32 + lhi * 8;
            float4 w0 = *(const float4*)wp;
            float4 w1 = *(const float4*)(wp + 4);
            float wv[8] = {w0.x, w0.y, w0.z, w0.w, w1.x, w1.y, w1.z, w1.w};
#pragma unroll
            for (int t = 0; t < 8; t++) {
                short h = f2bf_rne(wv[t]);
                wh[ct][kc][t] = h;
                wl[ct][kc][t] = f2bf_rne(wv[t] - bf2f(h));
            }
        }
    }

    for (int base = blockIdx.x * 16; base < nrows; base += gridDim.x * 16) {
        const int arow = base + l15;
        const bool av = arow < nrows;
        const float* xp = X + (size_t)arow * 128;
        bf16x8 ah[4], al[4];
#pragma unroll
        for (int kc = 0; kc < 4; kc++) {
            float4 a0 = make_float4(0.f, 0.f, 0.f, 0.f), a1 = a0;
            if (av) {
                a0 = *(const float4*)(xp + kc * 32 + lhi * 8);
                a1 = *(const float4*)(xp + kc * 32 + lhi * 8 + 4);
            }
            float xv[8] = {a0.x, a0.y, a0.z, a0.w, a1.x, a1.y, a1.z, a1.w};
#pragma unroll
            for (int t = 0; t < 8; t++) {
                short h = f2bf_rne(xv[t]);
                ah[kc][t] = h;
                al[kc][t] = f2bf_rne(xv[t] - bf2f(h));
            }
        }

        f32x4 acc[WCT];
#pragma unroll
        for (int ct = 0; ct < WCT; ct++) acc[ct] = (f32x4){0.f, 0.f, 0.f, 0.f};
#pragma unroll
        for (int kc = 0; kc < 4; kc++) {
#pragma unroll
            for (int ct = 0; ct < WCT; ct++) {
                acc[ct] = __builtin_amdgcn_mfma_f32_16x16x32_bf16(ah[kc], wh[ct][kc], acc[ct], 0, 0, 0);
                acc[ct] = __builtin_amdgcn_mfma_f32_16x16x32_bf16(ah[kc], wl[ct][kc], acc[ct], 0, 0, 0);
                acc[ct] = __builtin_amdgcn_mfma_f32_16x16x32_bf16(al[kc], wh[ct][kc], acc[ct], 0, 0, 0);
            }
        }

        float dv[4];
#pragma unroll
        for (int r = 0; r < 4; r++) {
            int row = base + lhi * 4 + r;
            dv[r] = (row < nrows) ? dinv[row] : 0.f;
        }
#pragma unroll
        for (int ct = 0; ct < WCT; ct++) {
            const int j = (wid * WCT + ct) * 16 + l15;
#pragma unroll
            for (int r = 0; r < 4; r++) {
                int row = base + lhi * 4 + r;
                if (row < nrows) G[(size_t)row * DO + j] = dv[r] * acc[ct][r];
            }
        }
    }
}

// One wave per node. DO=128: half-wave float4 (2 edges/step); DO=64: quarter-wave float4
// (4 edges/step). Unrolled so 4 independent gathers are in flight per lane (MLP=4).
template <int DO, bool LEAKY>
__global__ __launch_bounds__(THREADS)
void aggregate(const int* __restrict__ rowptr, const int* __restrict__ counts,
               const int* __restrict__ csr, const float* __restrict__ g,
               const float* __restrict__ dinv, const float* __restrict__ bias,
               float* __restrict__ out, int n) {
    const int lane = threadIdx.x & 63;
    const int node = blockIdx.x * (THREADS / 64) + (threadIdx.x >> 6);
    if (node >= n) return;
    const int beg = rowptr[node], cnt = counts[node];

    if (DO == 128) {
        const int half = lane >> 5;          // 0,1: which edge of the pair
        const int hl = lane & 31;            // feature quad within row
        float4 a0 = make_float4(0.f, 0.f, 0.f, 0.f);
        float4 a1 = a0, a2 = a0, a3 = a0;
        for (int base = 0; base < cnt; base += 64) {
            int m = cnt - base; if (m > 64) m = 64;
            int sv = (base + lane < cnt) ? csr[beg + base + lane] : 0;
            int i = 0;
            for (; i + 8 <= m; i += 8) {
                int s0 = __shfl(sv, i + half);
                int s1 = __shfl(sv, i + 2 + half);
                int s2 = __shfl(sv, i + 4 + half);
                int s3 = __shfl(sv, i + 6 + half);
                float4 v0 = *(const float4*)(g + (size_t)s0 * 128 + hl * 4);
                float4 v1 = *(const float4*)(g + (size_t)s1 * 128 + hl * 4);
                float4 v2 = *(const float4*)(g + (size_t)s2 * 128 + hl * 4);
                float4 v3 = *(const float4*)(g + (size_t)s3 * 128 + hl * 4);
                a0.x += v0.x; a0.y += v0.y; a0.z += v0.z; a0.w += v0.w;
                a1.x += v1.x; a1.y += v1.y; a1.z += v1.z; a1.w += v1.w;
                a2.x += v2.x; a2.y += v2.y; a2.z += v2.z; a2.w += v2.w;
                a3.x += v3.x; a3.y += v3.y; a3.z += v3.z; a3.w += v3.w;
            }
            for (; i < m; i += 2) {
                int idx = i + half;
                int s = __shfl(sv, idx < m ? idx : 0);
                if (idx < m) {
                    float4 v = *(const float4*)(g + (size_t)s * 128 + hl * 4);
                    a0.x += v.x; a0.y += v.y; a0.z += v.z; a0.w += v.w;
                }
            }
        }
        a0.x += a1.x + a2.x + a3.x;
        a0.y += a1.y + a2.y + a3.y;
        a0.z += a1.z + a2.z + a3.z;
        a0.w += a1.w + a2.w + a3.w;
        // combine the two halves (each summed a disjoint set of edges)
        a0.x += __shfl_xor(a0.x, 32);
        a0.y += __shfl_xor(a0.y, 32);
        a0.z += __shfl_xor(a0.z, 32);
        a0.w += __shfl_xor(a0.w, 32);
        if (half == 0) {
            float4 self = *(const float4*)(g + (size_t)node * 128 + hl * 4);
            float4 bv = ((const float4*)bias)[hl];
            float di = dinv[node];
            float4 r;
            r.x = di * (a0.x + self.x) + bv.x;
            r.y = di * (a0.y + self.y) + bv.y;
            r.z = di * (a0.z + self.z) + bv.z;
            r.w = di * (a0.w + self.w) + bv.w;
            if (LEAKY) {
                r.x = r.x > 0.f ? r.x : 0.01f * r.x;
                r.y = r.y > 0.f ? r.y : 0.01f * r.y;
                r.z = r.z > 0.f ? r.z : 0.01f * r.z;
                r.w = r.w > 0.f ? r.w : 0.01f * r.w;
            }
            *(float4*)(out + (size_t)node * 128 + hl * 4) = r;
        }
    } else {
        const int q = lane >> 4;             // 0..3: which edge of the quad
        const int ql = lane & 15;            // feature quad within row
        float4 a0 = make_float4(0.f, 0.f, 0.f, 0.f);
        float4 a1 = a0, a2 = a0, a3 = a0;
        for (int base = 0; base < cnt; base += 64) {
            int m = cnt - base; if (m > 64) m = 64;
            int sv = (base + lane < cnt) ? csr[beg + base + lane] : 0;
            int i = 0;
            for (; i + 16 <= m; i += 16) {
                int s0 = __shfl(sv, i + q);
                int s1 = __shfl(sv, i + 4 + q);
                int s2 = __shfl(sv, i + 8 + q);
                int s3 = __shfl(sv, i + 12 + q);
                float4 v0 = *(const float4*)(g + (size_t)s0 * 64 + ql * 4);
                float4 v1 = *(const float4*)(g + (size_t)s1 * 64 + ql * 4);
                float4 v2 = *(const float4*)(g + (size_t)s2 * 64 + ql * 4);
                float4 v3 = *(const float4*)(g + (size_t)s3 * 64 + ql * 4);
                a0.x += v0.x; a0.y += v0.y; a0.z += v0.z; a0.w += v0.w;
                a1.x += v1.x; a1.y += v1.y; a1.z += v1.z; a1.w += v1.w;
                a2.x += v2.x; a2.y += v2.y; a2.z += v2.z; a2.w += v2.w;
                a3.x += v3.x; a3.y += v3.y; a3.z += v3.z; a3.w += v3.w;
            }
            for (; i < m; i += 4) {
                int idx = i + q;
                int s = __shfl(sv, idx < m ? idx : 0);
                if (idx < m) {
                    float4 v = *(const float4*)(g + (size_t)s * 64 + ql * 4);
                    a0.x += v.x; a0.y += v.y; a0.z += v.z; a0.w += v.w;
                }
            }
        }
        a0.x += a1.x + a2.x + a3.x;
        a0.y += a1.y + a2.y + a3.y;
        a0.z += a1.z + a2.z + a3.z;
        a0.w += a1.w + a2.w + a3.w;
        a0.x += __shfl_xor(a0.x, 16); a0.x += __shfl_xor(a0.x, 32);
        a0.y += __shfl_xor(a0.y, 16); a0.y += __shfl_xor(a0.y, 32);
        a0.z += __shfl_xor(a0.z, 16); a0.z += __shfl_xor(a0.z, 32);
        a0.w += __shfl_xor(a0.w, 16); a0.w += __shfl_xor(a0.w, 32);
        if (q == 0) {
            float4 self = *(const float4*)(g + (size_t)node * 64 + ql * 4);
            float4 bv = ((const float4*)bias)[ql];
            float di = dinv[node];
            float4 r;
            r.x = di * (a0.x + self.x) + bv.x;
            r.y = di * (a0.y + self.y) + bv.y;
            r.z = di * (a0.z + self.z) + bv.z;
            r.w = di * (a0.w + self.w) + bv.w;
            if (LEAKY) {
                r.x = r.x > 0.f ? r.x : 0.01f * r.x;
                r.y = r.y > 0.f ? r.y : 0.01f * r.y;
                r.z = r.z > 0.f ? r.z : 0.01f * r.z;
                r.w = r.w > 0.f ? r.w : 0.01f * r.w;
            }
            *(float4*)(out + (size_t)node * 64 + ql * 4) = r;
        }
    }
}

extern "C" void kernel_launch(void* const* d_in, const int* in_sizes, int n_in,
                              void* d_out, int out_size, void* d_ws, size_t ws_size,
                              hipStream_t stream) {
    const float* x  = (const float*)d_in[0];
    const int*   ei = (const int*)d_in[1];
    const float* W1 = (const float*)d_in[2];
    const float* b1 = (const float*)d_in[3];
    const float* W2 = (const float*)d_in[4];
    const float* b2 = (const float*)d_in[5];

    const int N = in_sizes[0] / 128;
    const int E = in_sizes[1] / 2;
    const int* src = ei;
    const int* dst = ei + E;

    const int NB = (N + THREADS - 1) / THREADS;      // scan blocks (<= 512 required)

    char* ws = (char*)d_ws;
    size_t off = 0;
    auto alloc = [&](size_t bytes) { char* p = ws + off; off = (off + bytes + 511) & ~(size_t)511; return p; };
    int*   counts = (int*)alloc((size_t)N * 4);
    int*   rowptr = (int*)alloc((size_t)N * 4);
    int*   cursor = (int*)alloc((size_t)N * 4);
    int*   bsum   = (int*)alloc((size_t)NB * 4);
    int*   boff   = (int*)alloc((size_t)NB * 4);
    float* dinv   = (float*)alloc((size_t)N * 4);
    int*   csr    = (int*)alloc((size_t)E * 4);
    float* g1     = (float*)alloc((size_t)N * 128 * 4);
    float* g2     = g1;                               // g1 dead before gemm2 writes g2

    float* h1 = (float*)d_out;                        // N*128
    float* h2 = h1 + (size_t)N * 128;                 // N*64

    hipMemsetAsync(counts, 0, (size_t)N * 4, stream);

    // 4 edges/thread: e, e+T, e+2T, e+3T (only the last can be OOB)
    const int G4 = (E + 4 * THREADS - 1) / (4 * THREADS);
    const int T = G4 * THREADS;
    count_kernel<<<G4, THREADS, 0, stream>>>(dst, counts, E, T);
    scanA<<<NB, THREADS, 0, stream>>>(counts, rowptr, bsum, N);
    scanB<<<1, 512, 0, stream>>>(bsum, boff, NB);
    scanC<<<NB, THREADS, 0, stream>>>(rowptr, cursor, dinv, counts, boff, N);
    fill_kernel<<<G4, THREADS, 0, stream>>>(src, dst, cursor, csr, E, T);

    const int AGB = (N + (THREADS / 64) - 1) / (THREADS / 64);

    // ---- layer 1 ----
    gemm_mfma<128><<<2048, THREADS, 0, stream>>>(x, W1, dinv, g1, N);
    aggregate<128, true><<<AGB, THREADS, 0, stream>>>(rowptr, counts, csr, g1, dinv, b1, h1, N);

    // ---- layer 2 ----
    gemm_mfma<64><<<2048, THREADS, 0, stream>>>(h1, W2, dinv, g2, N);
    aggregate<64, false><<<AGB, THREADS, 0, stream>>>(rowptr, counts, csr, g2, dinv, b2, h2, N);
}

// Round 8
// 557.406 us; speedup vs baseline: 8.0386x; 1.0692x over previous
//
#include <hip/hip_runtime.h>

// GCN 2-layer, atomic-free aggregation via per-call CSR (counting sort by dst).
// out[i] = dinv[i]*(sum_{e:dst=i} g[src] + g[i]) + b, g = dinv * (X @ W^T).
// GEMMs: MFMA hi/lo bf16 split (3-term). fill's random 4B csr stores cost ~E*64B of
// HBM RMW traffic (cross-XCD line sharing, measured WRITE_SIZE=E*64B) -> structural;
// hidden by fusing fill with gemm1 (independent, both post-scanC) in one kernel.
// Aggregate: fully-predicated gather steps keep 8 loads in flight even in tails.

#define THREADS 256

typedef __attribute__((ext_vector_type(8))) short bf16x8;
typedef __attribute__((ext_vector_type(4))) float f32x4;

__device__ __forceinline__ short f2bf_rne(float f) {
    unsigned u = __builtin_bit_cast(unsigned, f);
    u = u + 0x7fffu + ((u >> 16) & 1u);
    return (short)(u >> 16);
}
__device__ __forceinline__ float bf2f(short h) {
    unsigned u = ((unsigned)(unsigned short)h) << 16;
    return __builtin_bit_cast(float, u);
}

// ---- CSR build: 4 edges/thread ----
__global__ __launch_bounds__(THREADS)
void count_kernel(const int* __restrict__ dst, int* __restrict__ counts, int E, int T) {
    int t = blockIdx.x * THREADS + threadIdx.x;
    int e0 = t, e1 = t + T, e2 = t + 2 * T, e3 = t + 3 * T;
    int d0 = dst[e0], d1 = dst[e1], d2 = dst[e2];
    bool v3 = e3 < E;
    int d3 = v3 ? dst[e3] : 0;
    atomicAdd(&counts[d0], 1);
    atomicAdd(&counts[d1], 1);
    atomicAdd(&counts[d2], 1);
    if (v3) atomicAdd(&counts[d3], 1);
}

__global__ __launch_bounds__(THREADS)
void scanA(const int* __restrict__ counts, int* __restrict__ rowptr,
           int* __restrict__ bsum, int n) {
    __shared__ int s[THREADS];
    int i = blockIdx.x * THREADS + threadIdx.x;
    int v = (i < n) ? counts[i] : 0;
    s[threadIdx.x] = v;
    __syncthreads();
    for (int off = 1; off < THREADS; off <<= 1) {
        int a = (threadIdx.x >= off) ? s[threadIdx.x - off] : 0;
        __syncthreads();
        s[threadIdx.x] += a;
        __syncthreads();
    }
    if (i < n) rowptr[i] = s[threadIdx.x] - v;          // exclusive
    if (threadIdx.x == THREADS - 1) bsum[blockIdx.x] = s[threadIdx.x];
}

__global__ __launch_bounds__(512)
void scanB(const int* __restrict__ bsum, int* __restrict__ boff, int nb) {
    __shared__ int s[512];
    int t = threadIdx.x;
    int v = (t < nb) ? bsum[t] : 0;
    s[t] = v;
    __syncthreads();
    for (int off = 1; off < 512; off <<= 1) {
        int a = (t >= off) ? s[t - off] : 0;
        __syncthreads();
        s[t] += a;
        __syncthreads();
    }
    if (t < nb) boff[t] = s[t] - v;
}

__global__ __launch_bounds__(THREADS)
void scanC(int* __restrict__ rowptr, int* __restrict__ cursor, float* __restrict__ dinv,
           const int* __restrict__ counts, const int* __restrict__ boff, int n) {
    int i = blockIdx.x * THREADS + threadIdx.x;
    if (i >= n) return;
    int r = rowptr[i] + boff[blockIdx.x];
    rowptr[i] = r;
    cursor[i] = r;
    dinv[i] = rsqrtf((float)counts[i] + 1.0f);
}

// ---- device bodies for the fused fill||gemm kernel ----
__device__ __forceinline__ void fill_body(int fbid, const int* __restrict__ src,
                                          const int* __restrict__ dst, int* __restrict__ cursor,
                                          int* __restrict__ csr, int E, int T) {
    int t = fbid * THREADS + threadIdx.x;
    int e0 = t, e1 = t + T, e2 = t + 2 * T, e3 = t + 3 * T;
    int d0 = dst[e0], d1 = dst[e1], d2 = dst[e2];
    int s0 = src[e0], s1 = src[e1], s2 = src[e2];
    bool v3 = e3 < E;
    int d3 = v3 ? dst[e3] : 0;
    int s3 = v3 ? src[e3] : 0;
    int p0 = atomicAdd(&cursor[d0], 1);
    int p1 = atomicAdd(&cursor[d1], 1);
    int p2 = atomicAdd(&cursor[d2], 1);
    int p3 = v3 ? atomicAdd(&cursor[d3], 1) : 0;
    csr[p0] = s0;
    csr[p1] = s1;
    csr[p2] = s2;
    if (v3) csr[p3] = s3;
}

// G[i][j] = dinv[i] * sum_k X[i][k] * W[j][k];  W row-major [DO][128], K=128.
template <int DO>
__device__ __forceinline__ void gemm_body(int gbid, int nGemm,
                                          const float* __restrict__ X, const float* __restrict__ W,
                                          const float* __restrict__ dinv, float* __restrict__ G,
                                          int nrows) {
    constexpr int WCT = DO / 64;
    const int wid = threadIdx.x >> 6;
    const int lane = threadIdx.x & 63;
    const int l15 = lane & 15;
    const int lhi = lane >> 4;

    bf16x8 wh[WCT][4], wl[WCT][4];
#pragma unroll
    for (int ct = 0; ct < WCT; ct++) {
        const int j = (wid * WCT + ct) * 16 + l15;
#pragma unroll
        for (int kc = 0; kc < 4; kc++) {
            const float* wp = W + (size_t)j * 128 + kc * 32 + lhi * 8;
            float4 w0 = *(const float4*)wp;
            float4 w1 = *(const float4*)(wp + 4);
            float wv[8] = {w0.x, w0.y, w0.z, w0.w, w1.x, w1.y, w1.z, w1.w};
#pragma unroll
            for (int t = 0; t < 8; t++) {
                short h = f2bf_rne(wv[t]);
                wh[ct][kc][t] = h;
                wl[ct][kc][t] = f2bf_rne(wv[t] - bf2f(h));
            }
        }
    }

    for (int base = gbid * 16; base < nrows; base += nGemm * 16) {
        const int arow = base + l15;
        const bool av = arow < nrows;
        const float* xp = X + (size_t)arow * 128;
        bf16x8 ah[4], al[4];
#pragma unroll
        for (int kc = 0; kc < 4; kc++) {
            float4 a0 = make_float4(0.f, 0.f, 0.f, 0.f), a1 = a0;
            if (av) {
                a0 = *(const float4*)(xp + kc * 32 + lhi * 8);
                a1 = *(const float4*)(xp + kc * 32 + lhi * 8 + 4);
            }
            float xv[8] = {a0.x, a0.y, a0.z, a0.w, a1.x, a1.y, a1.z, a1.w};
#pragma unroll
            for (int t = 0; t < 8; t++) {
                short h = f2bf_rne(xv[t]);
                ah[kc][t] = h;
                al[kc][t] = f2bf_rne(xv[t] - bf2f(h));
            }
        }

        f32x4 acc[WCT];
#pragma unroll
        for (int ct = 0; ct < WCT; ct++) acc[ct] = (f32x4){0.f, 0.f, 0.f, 0.f};
#pragma unroll
        for (int kc = 0; kc < 4; kc++) {
#pragma unroll
            for (int ct = 0; ct < WCT; ct++) {
                acc[ct] = __builtin_amdgcn_mfma_f32_16x16x32_bf16(ah[kc], wh[ct][kc], acc[ct], 0, 0, 0);
                acc[ct] = __builtin_amdgcn_mfma_f32_16x16x32_bf16(ah[kc], wl[ct][kc], acc[ct], 0, 0, 0);
                acc[ct] = __builtin_amdgcn_mfma_f32_16x16x32_bf16(al[kc], wh[ct][kc], acc[ct], 0, 0, 0);
            }
        }

        float dv[4];
#pragma unroll
        for (int r = 0; r < 4; r++) {
            int row = base + lhi * 4 + r;
            dv[r] = (row < nrows) ? dinv[row] : 0.f;
        }
#pragma unroll
        for (int ct = 0; ct < WCT; ct++) {
            const int j = (wid * WCT + ct) * 16 + l15;
#pragma unroll
            for (int r = 0; r < 4; r++) {
                int row = base + lhi * 4 + r;
                if (row < nrows) G[(size_t)row * DO + j] = dv[r] * acc[ct][r];
            }
        }
    }
}

// Fused: even blocks run fill, odd blocks run gemm1 (both depend only on scanC).
__global__ __launch_bounds__(THREADS)
void fused_fill_gemm1(const int* __restrict__ src, const int* __restrict__ dst,
                      int* __restrict__ cursor, int* __restrict__ csr, int E, int T,
                      const float* __restrict__ X, const float* __restrict__ W,
                      const float* __restrict__ dinv, float* __restrict__ G,
                      int nrows, int nGemm) {
    int bid = blockIdx.x;
    if ((bid & 1) == 0) fill_body(bid >> 1, src, dst, cursor, csr, E, T);
    else gemm_body<128>(bid >> 1, nGemm, X, W, dinv, G, nrows);
}

__global__ __launch_bounds__(THREADS)
void gemm_mfma64(const float* __restrict__ X, const float* __restrict__ W,
                 const float* __restrict__ dinv, float* __restrict__ G, int nrows) {
    gemm_body<64>(blockIdx.x, gridDim.x, X, W, dinv, G, nrows);
}

// One wave per node; fully-predicated gather steps keep 8 independent loads in
// flight regardless of cnt (mean in-degree 16 => tails matter).
template <int DO, bool LEAKY>
__global__ __launch_bounds__(THREADS)
void aggregate(const int* __restrict__ rowptr, const int* __restrict__ counts,
               const int* __restrict__ csr, const float* __restrict__ g,
               const float* __restrict__ dinv, const float* __restrict__ bias,
               float* __restrict__ out, int n) {
    const int lane = threadIdx.x & 63;
    const int node = blockIdx.x * (THREADS / 64) + (threadIdx.x >> 6);
    if (node >= n) return;
    const int beg = rowptr[node], cnt = counts[node];

    if (DO == 128) {
        const int half = lane >> 5;          // which edge of the pair
        const int hl = lane & 31;            // feature quad within row
        float4 a[8];
#pragma unroll
        for (int t = 0; t < 8; t++) a[t] = make_float4(0.f, 0.f, 0.f, 0.f);
        for (int base = 0; base < cnt; base += 64) {
            int m = cnt - base; if (m > 64) m = 64;
            int sv = (base + lane < cnt) ? csr[beg + base + lane] : 0;
            for (int i = 0; i < m; i += 16) {
#pragma unroll
                for (int t = 0; t < 8; t++) {
                    int idx = i + 2 * t + half;
                    int s = __shfl(sv, idx & 63);
                    if (idx < m) {
                        float4 v = *(const float4*)(g + (size_t)s * 128 + hl * 4);
                        a[t].x += v.x; a[t].y += v.y; a[t].z += v.z; a[t].w += v.w;
                    }
                }
            }
        }
#pragma unroll
        for (int t = 1; t < 8; t++) {
            a[0].x += a[t].x; a[0].y += a[t].y; a[0].z += a[t].z; a[0].w += a[t].w;
        }
        a[0].x += __shfl_xor(a[0].x, 32);
        a[0].y += __shfl_xor(a[0].y, 32);
        a[0].z += __shfl_xor(a[0].z, 32);
        a[0].w += __shfl_xor(a[0].w, 32);
        if (half == 0) {
            float4 self = *(const float4*)(g + (size_t)node * 128 + hl * 4);
            float4 bv = ((const float4*)bias)[hl];
            float di = dinv[node];
            float4 r;
            r.x = di * (a[0].x + self.x) + bv.x;
            r.y = di * (a[0].y + self.y) + bv.y;
            r.z = di * (a[0].z + self.z) + bv.z;
            r.w = di * (a[0].w + self.w) + bv.w;
            if (LEAKY) {
                r.x = r.x > 0.f ? r.x : 0.01f * r.x;
                r.y = r.y > 0.f ? r.y : 0.01f * r.y;
                r.z = r.z > 0.f ? r.z : 0.01f * r.z;
                r.w = r.w > 0.f ? r.w : 0.01f * r.w;
            }
            *(float4*)(out + (size_t)node * 128 + hl * 4) = r;
        }
    } else {
        const int q = lane >> 4;             // which edge of the quad
        const int ql = lane & 15;            // feature quad within row
        float4 a[8];
#pragma unroll
        for (int t = 0; t < 8; t++) a[t] = make_float4(0.f, 0.f, 0.f, 0.f);
        for (int base = 0; base < cnt; base += 64) {
            int m = cnt - base; if (m > 64) m = 64;
            int sv = (base + lane < cnt) ? csr[beg + base + lane] : 0;
            for (int i = 0; i < m; i += 32) {
#pragma unroll
                for (int t = 0; t < 8; t++) {
                    int idx = i + 4 * t + q;
                    int s = __shfl(sv, idx & 63);
                    if (idx < m) {
                        float4 v = *(const float4*)(g + (size_t)s * 64 + ql * 4);
                        a[t].x += v.x; a[t].y += v.y; a[t].z += v.z; a[t].w += v.w;
                    }
                }
            }
        }
#pragma unroll
        for (int t = 1; t < 8; t++) {
            a[0].x += a[t].x; a[0].y += a[t].y; a[0].z += a[t].z; a[0].w += a[t].w;
        }
        a[0].x += __shfl_xor(a[0].x, 16); a[0].x += __shfl_xor(a[0].x, 32);
        a[0].y += __shfl_xor(a[0].y, 16); a[0].y += __shfl_xor(a[0].y, 32);
        a[0].z += __shfl_xor(a[0].z, 16); a[0].z += __shfl_xor(a[0].z, 32);
        a[0].w += __shfl_xor(a[0].w, 16); a[0].w += __shfl_xor(a[0].w, 32);
        if (q == 0) {
            float4 self = *(const float4*)(g + (size_t)node * 64 + ql * 4);
            float4 bv = ((const float4*)bias)[ql];
            float di = dinv[node];
            float4 r;
            r.x = di * (a[0].x + self.x) + bv.x;
            r.y = di * (a[0].y + self.y) + bv.y;
            r.z = di * (a[0].z + self.z) + bv.z;
            r.w = di * (a[0].w + self.w) + bv.w;
            if (LEAKY) {
                r.x = r.x > 0.f ? r.x : 0.01f * r.x;
                r.y = r.y > 0.f ? r.y : 0.01f * r.y;
                r.z = r.z > 0.f ? r.z : 0.01f * r.z;
                r.w = r.w > 0.f ? r.w : 0.01f * r.w;
            }
            *(float4*)(out + (size_t)node * 64 + ql * 4) = r;
        }
    }
}

extern "C" void kernel_launch(void* const* d_in, const int* in_sizes, int n_in,
                              void* d_out, int out_size, void* d_ws, size_t ws_size,
                              hipStream_t stream) {
    const float* x  = (const float*)d_in[0];
    const int*   ei = (const int*)d_in[1];
    const float* W1 = (const float*)d_in[2];
    const float* b1 = (const float*)d_in[3];
    const float* W2 = (const float*)d_in[4];
    const float* b2 = (const float*)d_in[5];

    const int N = in_sizes[0] / 128;
    const int E = in_sizes[1] / 2;
    const int* src = ei;
    const int* dst = ei + E;

    const int NB = (N + THREADS - 1) / THREADS;      // scan blocks (<= 512 required)

    char* ws = (char*)d_ws;
    size_t off = 0;
    auto alloc = [&](size_t bytes) { char* p = ws + off; off = (off + bytes + 511) & ~(size_t)511; return p; };
    int*   counts = (int*)alloc((size_t)N * 4);
    int*   rowptr = (int*)alloc((size_t)N * 4);
    int*   cursor = (int*)alloc((size_t)N * 4);
    int*   bsum   = (int*)alloc((size_t)NB * 4);
    int*   boff   = (int*)alloc((size_t)NB * 4);
    float* dinv   = (float*)alloc((size_t)N * 4);
    int*   csr    = (int*)alloc((size_t)E * 4);
    float* g1     = (float*)alloc((size_t)N * 128 * 4);
    float* g2     = g1;                               // g1 dead before gemm2 writes g2

    float* h1 = (float*)d_out;                        // N*128
    float* h2 = h1 + (size_t)N * 128;                 // N*64

    hipMemsetAsync(counts, 0, (size_t)N * 4, stream);

    // 4 edges/thread: e, e+T, e+2T, e+3T (only the last can be OOB)
    const int G4 = (E + 4 * THREADS - 1) / (4 * THREADS);
    const int T = G4 * THREADS;
    count_kernel<<<G4, THREADS, 0, stream>>>(dst, counts, E, T);
    scanA<<<NB, THREADS, 0, stream>>>(counts, rowptr, bsum, N);
    scanB<<<1, 512, 0, stream>>>(bsum, boff, NB);
    scanC<<<NB, THREADS, 0, stream>>>(rowptr, cursor, dinv, counts, boff, N);

    const int AGB = (N + (THREADS / 64) - 1) / (THREADS / 64);

    // ---- layer 1: fill || gemm1 fused (independent after scanC) ----
    fused_fill_gemm1<<<2 * G4, THREADS, 0, stream>>>(src, dst, cursor, csr, E, T,
                                                     x, W1, dinv, g1, N, G4);
    aggregate<128, true><<<AGB, THREADS, 0, stream>>>(rowptr, counts, csr, g1, dinv, b1, h1, N);

    // ---- layer 2 ----
    gemm_mfma64<<<2048, THREADS, 0, stream>>>(h1, W2, dinv, g2, N);
    aggregate<64, false><<<AGB, THREADS, 0, stream>>>(rowptr, counts, csr, g2, dinv, b2, h2, N);
}